// Round 1
// baseline (5792.084 us; speedup 1.0000x reference)
//
#include <hip/hip_runtime.h>
#include <cstdint>
#include <cstddef>

#define NN 100000
#define EE 1600000
#define DIM 128

// ---------------------------------------------------------------------------
// Edge-index loads: handle both int32 and int64 storage. A detection kernel
// decides once per launch (flag in workspace), each consumer branches on it.
// ---------------------------------------------------------------------------
__device__ __forceinline__ int load_idx(const void* edges, int i64, long long pos) {
  if (i64) return (int)((const long long*)edges)[pos];
  return ((const int*)edges)[pos];
}

__global__ void detect_i64_kernel(const int* __restrict__ e32, int* __restrict__ flag) {
  __shared__ int any_nz;
  if (threadIdx.x == 0) any_nz = 0;
  __syncthreads();
  // int64 little-endian => high 32-bit word of every entry is 0 (values < 2^31).
  // int32 => odd words are random src values in [0,100000): all-zero is impossible.
  if (e32[2 * threadIdx.x + 1] != 0) any_nz = 1;
  __syncthreads();
  if (threadIdx.x == 0) *flag = (any_nz == 0) ? 1 : 0;
}

// ---------------------------------------------------------------------------
// Degree: deg[dst] += 1 (counts <= 1.6M, exact in f32)
// ---------------------------------------------------------------------------
__global__ void deg_kernel(const void* __restrict__ edges, const int* __restrict__ i64f,
                           float* __restrict__ deg) {
  int i = blockIdx.x * blockDim.x + threadIdx.x;
  if (i >= EE) return;
  int i64 = *i64f;
  int d = load_idx(edges, i64, (long long)EE + i);
  if ((unsigned)d < NN) atomicAdd(&deg[d], 1.0f);
}

__global__ void rdeg_kernel(const float* __restrict__ deg, float* __restrict__ rdeg) {
  int i = blockIdx.x * blockDim.x + threadIdx.x;
  if (i < NN) rdeg[i] = 1.0f / fmaxf(deg[i], 1.0f);
}

// ---------------------------------------------------------------------------
// Scatter: agg[dst] += h[src]   (32 threads per edge, float4 chunks)
// ---------------------------------------------------------------------------
__global__ __launch_bounds__(256) void scatter_kernel(
    const void* __restrict__ edges, const int* __restrict__ i64f,
    const float* __restrict__ h, float* __restrict__ agg) {
  long long t = (long long)blockIdx.x * blockDim.x + threadIdx.x;
  long long e = t >> 5;
  int c = ((int)t & 31) << 2;
  if (e >= EE) return;
  int i64 = *i64f;
  int s = load_idx(edges, i64, e);
  int d = load_idx(edges, i64, (long long)EE + e);
  if ((unsigned)s >= NN || (unsigned)d >= NN) return;
  float4 v = *(const float4*)(h + (size_t)s * DIM + c);
  float* o = agg + (size_t)d * DIM + c;
  atomicAdd(o + 0, v.x);
  atomicAdd(o + 1, v.y);
  atomicAdd(o + 2, v.z);
  atomicAdd(o + 3, v.w);
}

// ---------------------------------------------------------------------------
// Dense: out = act( (agg*rdeg) @ Wl + bl + h @ Wr )
// 16 nodes per block, 256 threads: thread (j = t&127, ng = t>>7) computes
// column j of 8 nodes. Activations staged in LDS (broadcast reads),
// weights streamed from global (L2-resident).
// Safe for in-place h == out: each block stages its own rows before writing.
// ---------------------------------------------------------------------------
template <bool RELU>
__global__ __launch_bounds__(256) void dense_kernel(
    const float* __restrict__ agg, const float* __restrict__ rdeg,
    const float* __restrict__ h, const float* __restrict__ Wl,
    const float* __restrict__ bl, const float* __restrict__ Wr,
    float* __restrict__ out, int n) {
  __shared__ float a_sh[16][DIM];
  __shared__ float h_sh[16][DIM];
  const int t = threadIdx.x;
  const int base = blockIdx.x * 16;

#pragma unroll
  for (int it = 0; it < 2; ++it) {
    int p4 = t + it * 256;  // float4 index within 16x128 = 512 float4
    int r = p4 >> 5;
    int c4 = p4 & 31;
    int row = base + r;
    float4 av = make_float4(0.f, 0.f, 0.f, 0.f);
    float4 hv = av;
    if (row < n) {
      float rd = rdeg[row];
      av = ((const float4*)(agg + (size_t)row * DIM))[c4];
      av.x *= rd; av.y *= rd; av.z *= rd; av.w *= rd;
      hv = ((const float4*)(h + (size_t)row * DIM))[c4];
    }
    *(float4*)&a_sh[r][c4 * 4] = av;
    *(float4*)&h_sh[r][c4 * 4] = hv;
  }
  __syncthreads();

  const int j = t & (DIM - 1);
  const int ng = t >> 7;  // node group 0/1
  float acc[8];
  const float bias = bl[j];
#pragma unroll
  for (int r = 0; r < 8; ++r) acc[r] = bias;

  for (int k = 0; k < DIM; k += 4) {
    float wl0 = Wl[(k + 0) * DIM + j], wl1 = Wl[(k + 1) * DIM + j];
    float wl2 = Wl[(k + 2) * DIM + j], wl3 = Wl[(k + 3) * DIM + j];
    float wr0 = Wr[(k + 0) * DIM + j], wr1 = Wr[(k + 1) * DIM + j];
    float wr2 = Wr[(k + 2) * DIM + j], wr3 = Wr[(k + 3) * DIM + j];
#pragma unroll
    for (int r = 0; r < 8; ++r) {
      const int nr = ng * 8 + r;
      float4 a4 = *(const float4*)&a_sh[nr][k];
      float4 h4 = *(const float4*)&h_sh[nr][k];
      acc[r] = fmaf(a4.x, wl0, acc[r]);
      acc[r] = fmaf(a4.y, wl1, acc[r]);
      acc[r] = fmaf(a4.z, wl2, acc[r]);
      acc[r] = fmaf(a4.w, wl3, acc[r]);
      acc[r] = fmaf(h4.x, wr0, acc[r]);
      acc[r] = fmaf(h4.y, wr1, acc[r]);
      acc[r] = fmaf(h4.z, wr2, acc[r]);
      acc[r] = fmaf(h4.w, wr3, acc[r]);
    }
  }

#pragma unroll
  for (int r = 0; r < 8; ++r) {
    float v = acc[r];
    if (RELU) v = fmaxf(v, 0.f);
    int row = base + ng * 8 + r;
    if (row < n) out[(size_t)row * DIM + j] = v;
  }
}

// ---------------------------------------------------------------------------
extern "C" void kernel_launch(void* const* d_in, const int* in_sizes, int n_in,
                              void* d_out, int out_size, void* d_ws, size_t ws_size,
                              hipStream_t stream) {
  const float* x   = (const float*)d_in[0];
  const void* edges = d_in[1];
  const float* W1l = (const float*)d_in[2];
  const float* b1l = (const float*)d_in[3];
  const float* W1r = (const float*)d_in[4];
  const float* W2l = (const float*)d_in[5];
  const float* b2l = (const float*)d_in[6];
  const float* W2r = (const float*)d_in[7];
  float* out = (float*)d_out;

  float* deg  = (float*)d_ws;                 // N
  float* rdeg = deg + NN;                     // N
  float* agg  = rdeg + NN;                    // N*128
  int* flag   = (int*)(agg + (size_t)NN * DIM);

  // zero deg + rdeg + agg in one contiguous memset
  hipMemsetAsync(d_ws, 0, (size_t)(2 * NN + (size_t)NN * DIM) * sizeof(float), stream);

  detect_i64_kernel<<<1, 256, 0, stream>>>((const int*)edges, flag);
  deg_kernel<<<(EE + 255) / 256, 256, 0, stream>>>(edges, flag, deg);
  rdeg_kernel<<<(NN + 255) / 256, 256, 0, stream>>>(deg, rdeg);

  const int scatter_blocks = (int)(((long long)EE * 32) / 256);  // divisible

  // ---- layer 1: h1 = relu((agg(x)/deg) @ W1l + b1l + x @ W1r) -> d_out
  scatter_kernel<<<scatter_blocks, 256, 0, stream>>>(edges, flag, x, agg);
  dense_kernel<true><<<(NN + 15) / 16, 256, 0, stream>>>(agg, rdeg, x, W1l, b1l, W1r, out, NN);

  // ---- layer 2: out = (agg(h1)/deg) @ W2l + b2l + h1 @ W2r  (in-place on d_out)
  hipMemsetAsync(agg, 0, (size_t)NN * DIM * sizeof(float), stream);
  scatter_kernel<<<scatter_blocks, 256, 0, stream>>>(edges, flag, out, agg);
  dense_kernel<false><<<(NN + 15) / 16, 256, 0, stream>>>(agg, rdeg, out, W2l, b2l, W2r, out, NN);
}

// Round 2
// 723.999 us; speedup vs baseline: 8.0001x; 8.0001x over previous
//
#include <hip/hip_runtime.h>
#include <cstdint>
#include <cstddef>

#define NN 100000
#define EE 1600000
#define DIM 128
#define SCAN_BLK 98   // ceil(100000 / 1024)

// ---------------------------------------------------------------------------
// Edge-index loads: handle both int32 and int64 storage. A detection kernel
// decides once per launch (flag in workspace), each consumer branches on it.
// ---------------------------------------------------------------------------
__device__ __forceinline__ int load_idx(const void* edges, int i64, long long pos) {
  if (i64) return (int)((const long long*)edges)[pos];
  return ((const int*)edges)[pos];
}

__global__ void detect_i64_kernel(const int* __restrict__ e32, int* __restrict__ flag) {
  __shared__ int any_nz;
  if (threadIdx.x == 0) any_nz = 0;
  __syncthreads();
  // int64 little-endian => high 32-bit word of every entry is 0 (values < 2^31).
  // int32 => odd words are random src values in [0,100000): all-zero impossible.
  if (e32[2 * threadIdx.x + 1] != 0) any_nz = 1;
  __syncthreads();
  if (threadIdx.x == 0) *flag = (any_nz == 0) ? 1 : 0;
}

// ---------------------------------------------------------------------------
// Degree (int atomics) — shared by both layers.
// ---------------------------------------------------------------------------
__global__ void deg_kernel(const void* __restrict__ edges, const int* __restrict__ i64f,
                           int* __restrict__ deg) {
  int i = blockIdx.x * blockDim.x + threadIdx.x;
  if (i >= EE) return;
  int d = load_idx(edges, *i64f, (long long)EE + i);
  if ((unsigned)d < NN) atomicAdd(&deg[d], 1);
}

__global__ void rdeg_kernel(const int* __restrict__ deg, float* __restrict__ rdeg) {
  int i = blockIdx.x * blockDim.x + threadIdx.x;
  if (i < NN) rdeg[i] = 1.0f / fmaxf((float)deg[i], 1.0f);
}

// ---------------------------------------------------------------------------
// Exclusive prefix sum over deg[0..N) -> offsets[0..N], three tiny kernels.
// ---------------------------------------------------------------------------
__global__ void scan1_kernel(const int* __restrict__ deg, int* __restrict__ partials) {
  __shared__ int sh[256];
  const int base = blockIdx.x * 1024;
  const int t = threadIdx.x;
  int s = 0;
#pragma unroll
  for (int k = 0; k < 4; ++k) {
    int i = base + t * 4 + k;
    if (i < NN) s += deg[i];
  }
  sh[t] = s;
  __syncthreads();
  for (int off = 128; off > 0; off >>= 1) {
    if (t < off) sh[t] += sh[t + off];
    __syncthreads();
  }
  if (t == 0) partials[blockIdx.x] = sh[0];
}

__global__ void scan2_kernel(int* __restrict__ partials, int nb) {
  if (threadIdx.x == 0 && blockIdx.x == 0) {
    int run = 0;
    for (int i = 0; i < nb; ++i) { int v = partials[i]; partials[i] = run; run += v; }
    partials[nb] = run;  // == E
  }
}

__global__ void scan3_kernel(const int* __restrict__ deg, const int* __restrict__ partials,
                             int* __restrict__ offsets, int* __restrict__ cursor) {
  __shared__ int sh[257];
  const int base = blockIdx.x * 1024;
  const int t = threadIdx.x;
  int v[4];
  int s = 0;
#pragma unroll
  for (int k = 0; k < 4; ++k) {
    int i = base + t * 4 + k;
    v[k] = (i < NN) ? deg[i] : 0;
    s += v[k];
  }
  if (t == 0) sh[0] = 0;
  sh[t + 1] = s;
  __syncthreads();
  for (int off = 1; off < 256; off <<= 1) {
    int val = sh[t + 1];
    int add = (t >= off) ? sh[t + 1 - off] : 0;
    __syncthreads();
    sh[t + 1] = val + add;
    __syncthreads();
  }
  int ex = sh[t] + partials[blockIdx.x];
#pragma unroll
  for (int k = 0; k < 4; ++k) {
    int i = base + t * 4 + k;
    if (i < NN) { offsets[i] = ex; cursor[i] = ex; ex += v[k]; }
  }
  if (blockIdx.x == gridDim.x - 1 && t == 255) offsets[NN] = partials[gridDim.x];
}

// ---------------------------------------------------------------------------
// CSR fill: csr_src[cursor[dst]++] = src  (1.6M int atomics)
// ---------------------------------------------------------------------------
__global__ void fill_kernel(const void* __restrict__ edges, const int* __restrict__ i64f,
                            int* __restrict__ cursor, int* __restrict__ csr_src) {
  int e = blockIdx.x * blockDim.x + threadIdx.x;
  if (e >= EE) return;
  int i64 = *i64f;
  int s = load_idx(edges, i64, e);
  int d = load_idx(edges, i64, (long long)EE + e);
  if ((unsigned)d >= NN) return;
  int pos = atomicAdd(&cursor[d], 1);
  csr_src[pos] = s;
}

// ---------------------------------------------------------------------------
// Gather-aggregate: one wave per node; lane owns 2 columns (float2).
// agg[node] = (1/max(deg,1)) * sum_{s in nbrs(node)} h[s]
// ---------------------------------------------------------------------------
__global__ __launch_bounds__(256) void gather_kernel(
    const int* __restrict__ offsets, const int* __restrict__ csr,
    const float* __restrict__ h, const float* __restrict__ rdeg,
    float* __restrict__ agg) {
  const int node = blockIdx.x * 4 + (threadIdx.x >> 6);
  const int lane = threadIdx.x & 63;
  if (node >= NN) return;
  const int beg = offsets[node];
  const int end = offsets[node + 1];
  float ax = 0.f, ay = 0.f;
  int p = beg;
  for (; p + 1 < end; p += 2) {
    int s0 = csr[p];
    int s1 = csr[p + 1];
    float2 v0 = *(const float2*)(h + (size_t)s0 * DIM + lane * 2);
    float2 v1 = *(const float2*)(h + (size_t)s1 * DIM + lane * 2);
    ax += v0.x + v1.x;
    ay += v0.y + v1.y;
  }
  if (p < end) {
    int s0 = csr[p];
    float2 v0 = *(const float2*)(h + (size_t)s0 * DIM + lane * 2);
    ax += v0.x;
    ay += v0.y;
  }
  const float rd = rdeg[node];
  float2 o;
  o.x = ax * rd;
  o.y = ay * rd;
  *(float2*)(agg + (size_t)node * DIM + lane * 2) = o;
}

// ---------------------------------------------------------------------------
// Dense: out = act( agg @ Wl + bl + h @ Wr )   (agg already mean-scaled)
// 16 nodes/block, 256 threads; safe for in-place h == out.
// ---------------------------------------------------------------------------
template <bool RELU>
__global__ __launch_bounds__(256) void dense_kernel(
    const float* __restrict__ agg, const float* __restrict__ h,
    const float* __restrict__ Wl, const float* __restrict__ bl,
    const float* __restrict__ Wr, float* __restrict__ out, int n) {
  __shared__ float a_sh[16][DIM];
  __shared__ float h_sh[16][DIM];
  const int t = threadIdx.x;
  const int base = blockIdx.x * 16;

#pragma unroll
  for (int it = 0; it < 2; ++it) {
    int p4 = t + it * 256;
    int r = p4 >> 5;
    int c4 = p4 & 31;
    int row = base + r;
    float4 av = make_float4(0.f, 0.f, 0.f, 0.f);
    float4 hv = av;
    if (row < n) {
      av = ((const float4*)(agg + (size_t)row * DIM))[c4];
      hv = ((const float4*)(h + (size_t)row * DIM))[c4];
    }
    *(float4*)&a_sh[r][c4 * 4] = av;
    *(float4*)&h_sh[r][c4 * 4] = hv;
  }
  __syncthreads();

  const int j = t & (DIM - 1);
  const int ng = t >> 7;
  float acc[8];
  const float bias = bl[j];
#pragma unroll
  for (int r = 0; r < 8; ++r) acc[r] = bias;

  for (int k = 0; k < DIM; k += 4) {
    float wl0 = Wl[(k + 0) * DIM + j], wl1 = Wl[(k + 1) * DIM + j];
    float wl2 = Wl[(k + 2) * DIM + j], wl3 = Wl[(k + 3) * DIM + j];
    float wr0 = Wr[(k + 0) * DIM + j], wr1 = Wr[(k + 1) * DIM + j];
    float wr2 = Wr[(k + 2) * DIM + j], wr3 = Wr[(k + 3) * DIM + j];
#pragma unroll
    for (int r = 0; r < 8; ++r) {
      const int nr = ng * 8 + r;
      float4 a4 = *(const float4*)&a_sh[nr][k];
      float4 h4 = *(const float4*)&h_sh[nr][k];
      acc[r] = fmaf(a4.x, wl0, acc[r]);
      acc[r] = fmaf(a4.y, wl1, acc[r]);
      acc[r] = fmaf(a4.z, wl2, acc[r]);
      acc[r] = fmaf(a4.w, wl3, acc[r]);
      acc[r] = fmaf(h4.x, wr0, acc[r]);
      acc[r] = fmaf(h4.y, wr1, acc[r]);
      acc[r] = fmaf(h4.z, wr2, acc[r]);
      acc[r] = fmaf(h4.w, wr3, acc[r]);
    }
  }

#pragma unroll
  for (int r = 0; r < 8; ++r) {
    float v = acc[r];
    if (RELU) v = fmaxf(v, 0.f);
    int row = base + ng * 8 + r;
    if (row < n) out[(size_t)row * DIM + j] = v;
  }
}

// ---------------------------------------------------------------------------
extern "C" void kernel_launch(void* const* d_in, const int* in_sizes, int n_in,
                              void* d_out, int out_size, void* d_ws, size_t ws_size,
                              hipStream_t stream) {
  const float* x   = (const float*)d_in[0];
  const void* edges = d_in[1];
  const float* W1l = (const float*)d_in[2];
  const float* b1l = (const float*)d_in[3];
  const float* W1r = (const float*)d_in[4];
  const float* W2l = (const float*)d_in[5];
  const float* b2l = (const float*)d_in[6];
  const float* W2r = (const float*)d_in[7];
  float* out = (float*)d_out;

  // workspace layout
  int*   deg      = (int*)d_ws;                       // N
  int*   offsets  = deg + NN;                         // N+1
  int*   cursor   = offsets + NN + 1;                 // N
  int*   csr      = cursor + NN;                      // E
  int*   partials = csr + EE;                         // SCAN_BLK+1
  int*   flag     = partials + SCAN_BLK + 1;          // 1
  float* rdeg     = (float*)(flag + 1);               // N
  float* agg      = rdeg + NN;                        // N*128

  hipMemsetAsync(deg, 0, (size_t)NN * sizeof(int), stream);

  detect_i64_kernel<<<1, 256, 0, stream>>>((const int*)edges, flag);
  deg_kernel<<<(EE + 255) / 256, 256, 0, stream>>>(edges, flag, deg);
  rdeg_kernel<<<(NN + 255) / 256, 256, 0, stream>>>(deg, rdeg);

  scan1_kernel<<<SCAN_BLK, 256, 0, stream>>>(deg, partials);
  scan2_kernel<<<1, 64, 0, stream>>>(partials, SCAN_BLK);
  scan3_kernel<<<SCAN_BLK, 256, 0, stream>>>(deg, partials, offsets, cursor);
  fill_kernel<<<(EE + 255) / 256, 256, 0, stream>>>(edges, flag, cursor, csr);

  const int gather_blocks = (NN + 3) / 4;
  const int dense_blocks = (NN + 15) / 16;

  // ---- layer 1: h1 = relu(mean_agg(x) @ W1l + b1l + x @ W1r) -> d_out
  gather_kernel<<<gather_blocks, 256, 0, stream>>>(offsets, csr, x, rdeg, agg);
  dense_kernel<true><<<dense_blocks, 256, 0, stream>>>(agg, x, W1l, b1l, W1r, out, NN);

  // ---- layer 2: out = mean_agg(h1) @ W2l + b2l + h1 @ W2r  (in-place)
  gather_kernel<<<gather_blocks, 256, 0, stream>>>(offsets, csr, out, rdeg, agg);
  dense_kernel<false><<<dense_blocks, 256, 0, stream>>>(agg, out, W2l, b2l, W2r, out, NN);
}

// Round 3
// 573.154 us; speedup vs baseline: 10.1056x; 1.2632x over previous
//
#include <hip/hip_runtime.h>
#include <cstdint>
#include <cstddef>

#define NN 100000
#define EE 1600000
#define DIM 128
#define SCAN_BLK 98   // ceil(100000 / 1024)

typedef __attribute__((ext_vector_type(8))) short bf16x8;
typedef __attribute__((ext_vector_type(4))) float f32x4;

__device__ __forceinline__ unsigned short f2bf(float f) {
  union { float f; uint32_t u; } v; v.f = f;
  uint32_t r = v.u + 0x7FFF + ((v.u >> 16) & 1);  // RNE to bf16
  return (unsigned short)(r >> 16);
}
__device__ __forceinline__ float bf2f(unsigned short s) {
  union { uint32_t u; float f; } v; v.u = (uint32_t)s << 16;
  return v.f;
}

// split 8 f32 into bf16 hi + exact-residual bf16 lo fragments
__device__ __forceinline__ void split8v(f32x4 u0, f32x4 u1, bf16x8& hi, bf16x8& lo) {
#pragma unroll
  for (int i = 0; i < 4; ++i) {
    unsigned short h0 = f2bf(u0[i]);
    hi[i] = (short)h0;
    lo[i] = (short)f2bf(u0[i] - bf2f(h0));
    unsigned short h1 = f2bf(u1[i]);
    hi[i + 4] = (short)h1;
    lo[i + 4] = (short)f2bf(u1[i] - bf2f(h1));
  }
}

// ---------------------------------------------------------------------------
// Edge-index loads: handle both int32 and int64 storage.
// ---------------------------------------------------------------------------
__device__ __forceinline__ int load_idx(const void* edges, int i64, long long pos) {
  if (i64) return (int)((const long long*)edges)[pos];
  return ((const int*)edges)[pos];
}

__global__ void detect_i64_kernel(const int* __restrict__ e32, int* __restrict__ flag) {
  __shared__ int any_nz;
  if (threadIdx.x == 0) any_nz = 0;
  __syncthreads();
  if (e32[2 * threadIdx.x + 1] != 0) any_nz = 1;
  __syncthreads();
  if (threadIdx.x == 0) *flag = (any_nz == 0) ? 1 : 0;
}

// ---------------------------------------------------------------------------
// Degree + reciprocal degree
// ---------------------------------------------------------------------------
__global__ void deg_kernel(const void* __restrict__ edges, const int* __restrict__ i64f,
                           int* __restrict__ deg) {
  int i = blockIdx.x * blockDim.x + threadIdx.x;
  if (i >= EE) return;
  int d = load_idx(edges, *i64f, (long long)EE + i);
  if ((unsigned)d < NN) atomicAdd(&deg[d], 1);
}

__global__ void rdeg_kernel(const int* __restrict__ deg, float* __restrict__ rdeg) {
  int i = blockIdx.x * blockDim.x + threadIdx.x;
  if (i < NN) rdeg[i] = 1.0f / fmaxf((float)deg[i], 1.0f);
}

// ---------------------------------------------------------------------------
// Exclusive prefix sum over deg -> offsets
// ---------------------------------------------------------------------------
__global__ void scan1_kernel(const int* __restrict__ deg, int* __restrict__ partials) {
  __shared__ int sh[256];
  const int base = blockIdx.x * 1024;
  const int t = threadIdx.x;
  int s = 0;
#pragma unroll
  for (int k = 0; k < 4; ++k) {
    int i = base + t * 4 + k;
    if (i < NN) s += deg[i];
  }
  sh[t] = s;
  __syncthreads();
  for (int off = 128; off > 0; off >>= 1) {
    if (t < off) sh[t] += sh[t + off];
    __syncthreads();
  }
  if (t == 0) partials[blockIdx.x] = sh[0];
}

__global__ void scan2_kernel(int* __restrict__ partials, int nb) {
  if (threadIdx.x == 0 && blockIdx.x == 0) {
    int run = 0;
    for (int i = 0; i < nb; ++i) { int v = partials[i]; partials[i] = run; run += v; }
    partials[nb] = run;
  }
}

__global__ void scan3_kernel(const int* __restrict__ deg, const int* __restrict__ partials,
                             int* __restrict__ offsets, int* __restrict__ cursor) {
  __shared__ int sh[257];
  const int base = blockIdx.x * 1024;
  const int t = threadIdx.x;
  int v[4];
  int s = 0;
#pragma unroll
  for (int k = 0; k < 4; ++k) {
    int i = base + t * 4 + k;
    v[k] = (i < NN) ? deg[i] : 0;
    s += v[k];
  }
  if (t == 0) sh[0] = 0;
  sh[t + 1] = s;
  __syncthreads();
  for (int off = 1; off < 256; off <<= 1) {
    int val = sh[t + 1];
    int add = (t >= off) ? sh[t + 1 - off] : 0;
    __syncthreads();
    sh[t + 1] = val + add;
    __syncthreads();
  }
  int ex = sh[t] + partials[blockIdx.x];
#pragma unroll
  for (int k = 0; k < 4; ++k) {
    int i = base + t * 4 + k;
    if (i < NN) { offsets[i] = ex; cursor[i] = ex; ex += v[k]; }
  }
  if (blockIdx.x == gridDim.x - 1 && t == 255) offsets[NN] = partials[gridDim.x];
}

__global__ void fill_kernel(const void* __restrict__ edges, const int* __restrict__ i64f,
                            int* __restrict__ cursor, int* __restrict__ csr_src) {
  int e = blockIdx.x * blockDim.x + threadIdx.x;
  if (e >= EE) return;
  int i64 = *i64f;
  int s = load_idx(edges, i64, e);
  int d = load_idx(edges, i64, (long long)EE + e);
  if ((unsigned)d >= NN) return;
  int pos = atomicAdd(&cursor[d], 1);
  csr_src[pos] = s;
}

// ---------------------------------------------------------------------------
// Weight prep: Wt[mat][n][k] = bf16(W[k][n])  (transposed, bf16)
// ---------------------------------------------------------------------------
__global__ void wprep_kernel(const float* __restrict__ Wl, const float* __restrict__ Wr,
                             unsigned short* __restrict__ Wt) {
  int idx = blockIdx.x * 256 + threadIdx.x;   // 32768 total
  int mat = idx >> 14;
  int r = idx & 16383;
  int k = r >> 7, n = r & 127;
  const float* W = mat ? Wr : Wl;
  Wt[((size_t)(mat * 128 + n)) * 128 + k] = f2bf(W[k * 128 + n]);
}

// ---------------------------------------------------------------------------
// Gather-aggregate: one wave per node; wave-halves take alternating neighbors,
// lane owns a float4 column chunk. agg[node] = rdeg * sum h[nbr]
// ---------------------------------------------------------------------------
__global__ __launch_bounds__(256) void gather_kernel(
    const int* __restrict__ offsets, const int* __restrict__ csr,
    const float* __restrict__ h, const float* __restrict__ rdeg,
    float* __restrict__ agg) {
  const int node = blockIdx.x * 4 + (threadIdx.x >> 6);
  const int lane = threadIdx.x & 63;
  const int half = lane >> 5;
  const int c4 = lane & 31;
  if (node >= NN) return;
  const int beg = offsets[node];
  const int end = offsets[node + 1];
  f32x4 s = {0.f, 0.f, 0.f, 0.f};
  int p = beg + half;
  for (; p + 2 < end; p += 4) {
    int s0 = csr[p];
    int s1 = csr[p + 2];
    f32x4 v0 = *(const f32x4*)(h + (size_t)s0 * DIM + c4 * 4);
    f32x4 v1 = *(const f32x4*)(h + (size_t)s1 * DIM + c4 * 4);
    s += v0;
    s += v1;
  }
  if (p < end) {
    int s0 = csr[p];
    s += *(const f32x4*)(h + (size_t)s0 * DIM + c4 * 4);
  }
  f32x4 o;
#pragma unroll
  for (int i = 0; i < 4; ++i) o[i] = s[i] + __shfl_xor(s[i], 32, 64);
  if (half == 0) {
    float rd = rdeg[node];
#pragma unroll
    for (int i = 0; i < 4; ++i) o[i] *= rd;
    *(f32x4*)(agg + (size_t)node * DIM + c4 * 4) = o;
  }
}

// ---------------------------------------------------------------------------
// Dense via MFMA (split-A bf16): out = act(agg @ Wl + bl + h @ Wr)
// 64 rows x 128 cols per block (4 waves, wave owns 2 col-tiles).
// A loaded from global per fragment; weights held in VGPRs.
// ---------------------------------------------------------------------------
template <bool RELU>
__global__ __launch_bounds__(256, 2) void dense_mfma_kernel(
    const float* __restrict__ agg, const float* __restrict__ h,
    const unsigned short* __restrict__ Wt, const float* __restrict__ bl,
    float* __restrict__ out, int n) {
  const int t = threadIdx.x;
  const int wave = t >> 6, lane = t & 63;
  const int l15 = lane & 15, l4 = lane >> 4;
  const long long base = (long long)blockIdx.x * 64;

  // B fragments: [mat][kt][ntl]; n = lane&15, k = (lane>>4)*8 + j
  bf16x8 bfr[2][4][2];
#pragma unroll
  for (int mat = 0; mat < 2; ++mat)
#pragma unroll
    for (int kt = 0; kt < 4; ++kt)
#pragma unroll
      for (int ntl = 0; ntl < 2; ++ntl) {
        int ncol = (wave * 2 + ntl) * 16 + l15;
        int k0 = kt * 32 + l4 * 8;
        bfr[mat][kt][ntl] = *(const bf16x8*)(Wt + ((size_t)(mat * 128 + ncol)) * 128 + k0);
      }

  f32x4 acc[4][2];
#pragma unroll
  for (int ntl = 0; ntl < 2; ++ntl) {
    float b = bl[(wave * 2 + ntl) * 16 + l15];
#pragma unroll
    for (int rt = 0; rt < 4; ++rt) {
      f32x4 ib = {b, b, b, b};
      acc[rt][ntl] = ib;
    }
  }

#pragma unroll
  for (int kt = 0; kt < 4; ++kt) {
    const int k0 = kt * 32 + l4 * 8;
#pragma unroll
    for (int rt = 0; rt < 4; ++rt) {
      long long row = base + rt * 16 + l15;
      if (row >= n) row = n - 1;  // clamp: padded rows computed but never stored
      const float* pa = agg + row * DIM + k0;
      const float* ph = h + row * DIM + k0;
      f32x4 a0 = *(const f32x4*)pa;
      f32x4 a1 = *(const f32x4*)(pa + 4);
      f32x4 h0 = *(const f32x4*)ph;
      f32x4 h1 = *(const f32x4*)(ph + 4);
      bf16x8 ahi, alo, hhi, hlo;
      split8v(a0, a1, ahi, alo);
      split8v(h0, h1, hhi, hlo);
#pragma unroll
      for (int ntl = 0; ntl < 2; ++ntl) {
        acc[rt][ntl] = __builtin_amdgcn_mfma_f32_16x16x32_bf16(ahi, bfr[0][kt][ntl], acc[rt][ntl], 0, 0, 0);
        acc[rt][ntl] = __builtin_amdgcn_mfma_f32_16x16x32_bf16(alo, bfr[0][kt][ntl], acc[rt][ntl], 0, 0, 0);
        acc[rt][ntl] = __builtin_amdgcn_mfma_f32_16x16x32_bf16(hhi, bfr[1][kt][ntl], acc[rt][ntl], 0, 0, 0);
        acc[rt][ntl] = __builtin_amdgcn_mfma_f32_16x16x32_bf16(hlo, bfr[1][kt][ntl], acc[rt][ntl], 0, 0, 0);
      }
    }
  }

  __syncthreads();  // in-place (h == out) safety: all reads before any write

#pragma unroll
  for (int rt = 0; rt < 4; ++rt)
#pragma unroll
    for (int ntl = 0; ntl < 2; ++ntl) {
      const int col = (wave * 2 + ntl) * 16 + l15;
#pragma unroll
      for (int r = 0; r < 4; ++r) {
        long long row = base + rt * 16 + l4 * 4 + r;
        if (row < n) {
          float v = acc[rt][ntl][r];
          if (RELU) v = fmaxf(v, 0.f);
          out[row * DIM + col] = v;
        }
      }
    }
}

// ---------------------------------------------------------------------------
extern "C" void kernel_launch(void* const* d_in, const int* in_sizes, int n_in,
                              void* d_out, int out_size, void* d_ws, size_t ws_size,
                              hipStream_t stream) {
  const float* x   = (const float*)d_in[0];
  const void* edges = d_in[1];
  const float* W1l = (const float*)d_in[2];
  const float* b1l = (const float*)d_in[3];
  const float* W1r = (const float*)d_in[4];
  const float* W2l = (const float*)d_in[5];
  const float* b2l = (const float*)d_in[6];
  const float* W2r = (const float*)d_in[7];
  float* out = (float*)d_out;

  // workspace layout (Wt first for 16B alignment of fragments)
  unsigned short* Wt1 = (unsigned short*)d_ws;        // 2*128*128
  unsigned short* Wt2 = Wt1 + 2 * 128 * 128;          // 2*128*128
  int* deg      = (int*)(Wt2 + 2 * 128 * 128);        // N
  int* offsets  = deg + NN;                           // N+1
  int* cursor   = offsets + NN + 1;                   // N
  int* csr      = cursor + NN;                        // E
  int* partials = csr + EE;                           // SCAN_BLK+1
  int* flag     = partials + SCAN_BLK + 1;            // 1
  float* rdeg   = (float*)(flag + 1);                 // N
  float* agg    = (float*)((((uintptr_t)(rdeg + NN)) + 255) & ~(uintptr_t)255);  // N*128

  hipMemsetAsync(deg, 0, (size_t)NN * sizeof(int), stream);

  detect_i64_kernel<<<1, 256, 0, stream>>>((const int*)edges, flag);
  deg_kernel<<<(EE + 255) / 256, 256, 0, stream>>>(edges, flag, deg);
  rdeg_kernel<<<(NN + 255) / 256, 256, 0, stream>>>(deg, rdeg);

  scan1_kernel<<<SCAN_BLK, 256, 0, stream>>>(deg, partials);
  scan2_kernel<<<1, 64, 0, stream>>>(partials, SCAN_BLK);
  scan3_kernel<<<SCAN_BLK, 256, 0, stream>>>(deg, partials, offsets, cursor);
  fill_kernel<<<(EE + 255) / 256, 256, 0, stream>>>(edges, flag, cursor, csr);

  wprep_kernel<<<128, 256, 0, stream>>>(W1l, W1r, Wt1);
  wprep_kernel<<<128, 256, 0, stream>>>(W2l, W2r, Wt2);

  const int gather_blocks = (NN + 3) / 4;
  const int dense_blocks = (NN + 63) / 64;

  // ---- layer 1: h1 = relu(mean_agg(x) @ W1l + b1l + x @ W1r) -> d_out
  gather_kernel<<<gather_blocks, 256, 0, stream>>>(offsets, csr, x, rdeg, agg);
  dense_mfma_kernel<true><<<dense_blocks, 256, 0, stream>>>(agg, x, Wt1, b1l, out, NN);

  // ---- layer 2: out = mean_agg(h1) @ W2l + b2l + h1 @ W2r  (in-place)
  gather_kernel<<<gather_blocks, 256, 0, stream>>>(offsets, csr, out, rdeg, agg);
  dense_mfma_kernel<false><<<dense_blocks, 256, 0, stream>>>(agg, out, Wt2, b2l, out, NN);
}

// Round 4
// 441.662 us; speedup vs baseline: 13.1143x; 1.2977x over previous
//
#include <hip/hip_runtime.h>
#include <cstdint>
#include <cstddef>

#define NN 100000
#define EE 1600000
#define DIM 128
#define CAP 48        // ELL row capacity (mean deg 16; P(deg>48) ~ 5e-11 per node)
#define OVF_CAP 4096  // overflow edge capacity (expected 0 used)

typedef __attribute__((ext_vector_type(8))) short bf16x8;
typedef __attribute__((ext_vector_type(4))) float f32x4;

__device__ __forceinline__ unsigned short f2bf(float f) {
  union { float f; uint32_t u; } v; v.f = f;
  uint32_t r = v.u + 0x7FFF + ((v.u >> 16) & 1);  // RNE to bf16
  return (unsigned short)(r >> 16);
}
__device__ __forceinline__ float bf2f(unsigned short s) {
  union { uint32_t u; float f; } v; v.u = (uint32_t)s << 16;
  return v.f;
}

// split 8 f32 into bf16 hi + exact-residual bf16 lo fragments
__device__ __forceinline__ void split8v(f32x4 u0, f32x4 u1, bf16x8& hi, bf16x8& lo) {
#pragma unroll
  for (int i = 0; i < 4; ++i) {
    unsigned short h0 = f2bf(u0[i]);
    hi[i] = (short)h0;
    lo[i] = (short)f2bf(u0[i] - bf2f(h0));
    unsigned short h1 = f2bf(u1[i]);
    hi[i + 4] = (short)h1;
    lo[i + 4] = (short)f2bf(u1[i] - bf2f(h1));
  }
}

// ---------------------------------------------------------------------------
// Edge-index loads: handle both int32 and int64 storage.
// ---------------------------------------------------------------------------
__device__ __forceinline__ int load_idx(const void* edges, int i64, long long pos) {
  if (i64) return (int)((const long long*)edges)[pos];
  return ((const int*)edges)[pos];
}

__global__ void detect_i64_kernel(const int* __restrict__ e32, int* __restrict__ flag) {
  __shared__ int any_nz;
  if (threadIdx.x == 0) any_nz = 0;
  __syncthreads();
  if (e32[2 * threadIdx.x + 1] != 0) any_nz = 1;
  __syncthreads();
  if (threadIdx.x == 0) *flag = (any_nz == 0) ? 1 : 0;
}

// ---------------------------------------------------------------------------
// ELL fill: one atomic pass builds neighbor lists AND degree counts.
// ---------------------------------------------------------------------------
__global__ void ellfill_kernel(const void* __restrict__ edges, const int* __restrict__ i64f,
                               int* __restrict__ cnt, int* __restrict__ ell,
                               int* __restrict__ novf, int* __restrict__ ovf) {
  int e = blockIdx.x * 256 + threadIdx.x;
  if (e >= EE) return;
  int i64 = *i64f;
  int s = load_idx(edges, i64, e);
  int d = load_idx(edges, i64, (long long)EE + e);
  if ((unsigned)s >= NN || (unsigned)d >= NN) return;
  int pos = atomicAdd(&cnt[d], 1);
  if (pos < CAP) {
    ell[(size_t)d * CAP + pos] = s;
  } else {
    int oi = atomicAdd(novf, 1);
    if (oi < OVF_CAP) { ovf[oi * 2] = s; ovf[oi * 2 + 1] = d; }
  }
}

__global__ void rdeg_kernel(const int* __restrict__ cnt, float* __restrict__ rdeg) {
  int i = blockIdx.x * blockDim.x + threadIdx.x;
  if (i < NN) rdeg[i] = 1.0f / fmaxf((float)cnt[i], 1.0f);
}

// ---------------------------------------------------------------------------
// x (f32) -> bf16 shadow copy
// ---------------------------------------------------------------------------
__global__ void cast_kernel(const float* __restrict__ x, unsigned short* __restrict__ xb) {
  int i = blockIdx.x * 256 + threadIdx.x;  // one float4 per thread
  if (i >= NN * DIM / 4) return;
  f32x4 v = ((const f32x4*)x)[i];
  ushort4 o;
  o.x = f2bf(v[0]); o.y = f2bf(v[1]); o.z = f2bf(v[2]); o.w = f2bf(v[3]);
  ((ushort4*)xb)[i] = o;
}

// ---------------------------------------------------------------------------
// Gather-aggregate from ELL: one wave per node, halves take alternating
// neighbors, lane owns a 4-column chunk. agg[node] = rdeg * sum h[nbr]
// ---------------------------------------------------------------------------
template <bool BF>
__device__ __forceinline__ f32x4 load_row4(const void* h, int src, int c) {
  if (BF) {
    ushort4 v = *(const ushort4*)((const unsigned short*)h + (size_t)src * DIM + c * 4);
    f32x4 r;
    r[0] = bf2f(v.x); r[1] = bf2f(v.y); r[2] = bf2f(v.z); r[3] = bf2f(v.w);
    return r;
  } else {
    return *(const f32x4*)((const float*)h + (size_t)src * DIM + c * 4);
  }
}

template <bool BF>
__global__ __launch_bounds__(256) void gather_ell_kernel(
    const int* __restrict__ cnt, const int* __restrict__ ell,
    const void* __restrict__ h, const float* __restrict__ rdeg,
    float* __restrict__ agg) {
  const int node = blockIdx.x * 4 + (threadIdx.x >> 6);
  const int lane = threadIdx.x & 63;
  const int half = lane >> 5;
  const int c = lane & 31;
  if (node >= NN) return;
  int n = cnt[node];
  if (n > CAP) n = CAP;
  const int* row = ell + (size_t)node * CAP;
  f32x4 s = {0.f, 0.f, 0.f, 0.f};
  int p = half;
  for (; p + 2 < n; p += 4) {
    int s0 = row[p];
    int s1 = row[p + 2];
    s += load_row4<BF>(h, s0, c);
    s += load_row4<BF>(h, s1, c);
  }
  if (p < n) s += load_row4<BF>(h, row[p], c);
#pragma unroll
  for (int i = 0; i < 4; ++i) s[i] += __shfl_xor(s[i], 32, 64);
  if (half == 0) {
    float rd = rdeg[node];
    f32x4 o;
#pragma unroll
    for (int i = 0; i < 4; ++i) o[i] = s[i] * rd;
    *(f32x4*)(agg + (size_t)node * DIM + c * 4) = o;
  }
}

// ---------------------------------------------------------------------------
// Overflow fixup: agg[d] += h[s] * rdeg[d] for edges beyond ELL capacity.
// Fixed grid, early-out; expected novf == 0.
// ---------------------------------------------------------------------------
__global__ void ovf_kernel(const int* __restrict__ novf, const int* __restrict__ ovf,
                           const float* __restrict__ h, const float* __restrict__ rdeg,
                           float* __restrict__ agg) {
  int n = *novf;
  if (n > OVF_CAP) n = OVF_CAP;
  int idx = blockIdx.x * 256 + threadIdx.x;
  int e = idx >> 5;
  if (e >= n) return;
  int c = (idx & 31) * 4;
  int s = ovf[e * 2], d = ovf[e * 2 + 1];
  float rd = rdeg[d];
  const float* hp = h + (size_t)s * DIM + c;
  float* ap = agg + (size_t)d * DIM + c;
  atomicAdd(ap + 0, hp[0] * rd);
  atomicAdd(ap + 1, hp[1] * rd);
  atomicAdd(ap + 2, hp[2] * rd);
  atomicAdd(ap + 3, hp[3] * rd);
}

// ---------------------------------------------------------------------------
// Weight prep: Wt[mat][n][k] = bf16(W[k][n])  (transposed, bf16)
// ---------------------------------------------------------------------------
__global__ void wprep_kernel(const float* __restrict__ Wl, const float* __restrict__ Wr,
                             unsigned short* __restrict__ Wt) {
  int idx = blockIdx.x * 256 + threadIdx.x;  // 32768 total
  int mat = idx >> 14;
  int r = idx & 16383;
  int k = r >> 7, n = r & 127;
  const float* W = mat ? Wr : Wl;
  Wt[((size_t)(mat * 128 + n)) * 128 + k] = f2bf(W[k * 128 + n]);
}

// ---------------------------------------------------------------------------
// Dense via MFMA (split-A bf16): out = act(agg @ Wl + bl + h @ Wr)
// 64 rows x 128 cols per block. Optionally writes bf16 shadow copy (hb).
// ---------------------------------------------------------------------------
template <bool RELU>
__global__ __launch_bounds__(256, 2) void dense_mfma_kernel(
    const float* __restrict__ agg, const float* __restrict__ h,
    const unsigned short* __restrict__ Wt, const float* __restrict__ bl,
    float* __restrict__ out, unsigned short* __restrict__ hb, int n) {
  const int t = threadIdx.x;
  const int wave = t >> 6, lane = t & 63;
  const int l15 = lane & 15, l4 = lane >> 4;
  const long long base = (long long)blockIdx.x * 64;

  bf16x8 bfr[2][4][2];
#pragma unroll
  for (int mat = 0; mat < 2; ++mat)
#pragma unroll
    for (int kt = 0; kt < 4; ++kt)
#pragma unroll
      for (int ntl = 0; ntl < 2; ++ntl) {
        int ncol = (wave * 2 + ntl) * 16 + l15;
        int k0 = kt * 32 + l4 * 8;
        bfr[mat][kt][ntl] = *(const bf16x8*)(Wt + ((size_t)(mat * 128 + ncol)) * 128 + k0);
      }

  f32x4 acc[4][2];
#pragma unroll
  for (int ntl = 0; ntl < 2; ++ntl) {
    float b = bl[(wave * 2 + ntl) * 16 + l15];
#pragma unroll
    for (int rt = 0; rt < 4; ++rt) {
      f32x4 ib = {b, b, b, b};
      acc[rt][ntl] = ib;
    }
  }

#pragma unroll
  for (int kt = 0; kt < 4; ++kt) {
    const int k0 = kt * 32 + l4 * 8;
#pragma unroll
    for (int rt = 0; rt < 4; ++rt) {
      long long row = base + rt * 16 + l15;
      if (row >= n) row = n - 1;  // clamp: padded rows computed but never stored
      const float* pa = agg + row * DIM + k0;
      const float* ph = h + row * DIM + k0;
      f32x4 a0 = *(const f32x4*)pa;
      f32x4 a1 = *(const f32x4*)(pa + 4);
      f32x4 h0 = *(const f32x4*)ph;
      f32x4 h1 = *(const f32x4*)(ph + 4);
      bf16x8 ahi, alo, hhi, hlo;
      split8v(a0, a1, ahi, alo);
      split8v(h0, h1, hhi, hlo);
#pragma unroll
      for (int ntl = 0; ntl < 2; ++ntl) {
        acc[rt][ntl] = __builtin_amdgcn_mfma_f32_16x16x32_bf16(ahi, bfr[0][kt][ntl], acc[rt][ntl], 0, 0, 0);
        acc[rt][ntl] = __builtin_amdgcn_mfma_f32_16x16x32_bf16(alo, bfr[0][kt][ntl], acc[rt][ntl], 0, 0, 0);
        acc[rt][ntl] = __builtin_amdgcn_mfma_f32_16x16x32_bf16(hhi, bfr[1][kt][ntl], acc[rt][ntl], 0, 0, 0);
        acc[rt][ntl] = __builtin_amdgcn_mfma_f32_16x16x32_bf16(hlo, bfr[1][kt][ntl], acc[rt][ntl], 0, 0, 0);
      }
    }
  }

  __syncthreads();  // in-place (h == out) safety: all reads before any write

#pragma unroll
  for (int rt = 0; rt < 4; ++rt)
#pragma unroll
    for (int ntl = 0; ntl < 2; ++ntl) {
      const int col = (wave * 2 + ntl) * 16 + l15;
#pragma unroll
      for (int r = 0; r < 4; ++r) {
        long long row = base + rt * 16 + l4 * 4 + r;
        if (row < n) {
          float v = acc[rt][ntl][r];
          if (RELU) v = fmaxf(v, 0.f);
          out[row * DIM + col] = v;
          if (hb) hb[row * DIM + col] = f2bf(v);
        }
      }
    }
}

// ---------------------------------------------------------------------------
extern "C" void kernel_launch(void* const* d_in, const int* in_sizes, int n_in,
                              void* d_out, int out_size, void* d_ws, size_t ws_size,
                              hipStream_t stream) {
  const float* x   = (const float*)d_in[0];
  const void* edges = d_in[1];
  const float* W1l = (const float*)d_in[2];
  const float* b1l = (const float*)d_in[3];
  const float* W1r = (const float*)d_in[4];
  const float* W2l = (const float*)d_in[5];
  const float* b2l = (const float*)d_in[6];
  const float* W2r = (const float*)d_in[7];
  float* out = (float*)d_out;

  // ---- workspace layout (byte offsets, 16B-aligned chunks)
  char* p = (char*)d_ws;
  unsigned short* Wt1 = (unsigned short*)p;               p += 2 * 128 * 128 * 2;
  unsigned short* Wt2 = (unsigned short*)p;               p += 2 * 128 * 128 * 2;
  int* cnt  = (int*)p;                                    p += (size_t)NN * 4;
  int* novf = (int*)p;                                    p += 4;
  int* flag = (int*)p;                                    p += 4;
  p = (char*)(((uintptr_t)p + 15) & ~(uintptr_t)15);
  int* ovf = (int*)p;                                     p += (size_t)OVF_CAP * 2 * 4;
  float* rdeg = (float*)p;                                p += (size_t)NN * 4;
  p = (char*)(((uintptr_t)p + 255) & ~(uintptr_t)255);
  int* ell = (int*)p;                                     p += (size_t)NN * CAP * 4;
  p = (char*)(((uintptr_t)p + 255) & ~(uintptr_t)255);
  float* agg = (float*)p;                                 p += (size_t)NN * DIM * 4;
  size_t need_base = (size_t)(p - (char*)d_ws);
  unsigned short* hb = (unsigned short*)p;                p += (size_t)NN * DIM * 2;
  size_t need_full = (size_t)(p - (char*)d_ws);
  const bool use_bf16 = (ws_size >= need_full) && (need_base < ws_size);

  // zero cnt + novf + flag in one memset
  hipMemsetAsync(cnt, 0, ((size_t)NN + 2) * 4, stream);

  detect_i64_kernel<<<1, 256, 0, stream>>>((const int*)edges, flag);
  ellfill_kernel<<<(EE + 255) / 256, 256, 0, stream>>>(edges, flag, cnt, ell, novf, ovf);
  rdeg_kernel<<<(NN + 255) / 256, 256, 0, stream>>>(cnt, rdeg);

  wprep_kernel<<<128, 256, 0, stream>>>(W1l, W1r, Wt1);
  wprep_kernel<<<128, 256, 0, stream>>>(W2l, W2r, Wt2);

  const int gather_blocks = (NN + 3) / 4;
  const int dense_blocks = (NN + 63) / 64;
  const int ovf_blocks = OVF_CAP * 32 / 256;

  if (use_bf16) {
    cast_kernel<<<(NN * DIM / 4 + 255) / 256, 256, 0, stream>>>(x, hb);
    // ---- layer 1
    gather_ell_kernel<true><<<gather_blocks, 256, 0, stream>>>(cnt, ell, hb, rdeg, agg);
    ovf_kernel<<<ovf_blocks, 256, 0, stream>>>(novf, ovf, x, rdeg, agg);
    dense_mfma_kernel<true><<<dense_blocks, 256, 0, stream>>>(agg, x, Wt1, b1l, out, hb, NN);
    // ---- layer 2 (in-place)
    gather_ell_kernel<true><<<gather_blocks, 256, 0, stream>>>(cnt, ell, hb, rdeg, agg);
    ovf_kernel<<<ovf_blocks, 256, 0, stream>>>(novf, ovf, out, rdeg, agg);
    dense_mfma_kernel<false><<<dense_blocks, 256, 0, stream>>>(agg, out, Wt2, b2l, out, nullptr, NN);
  } else {
    gather_ell_kernel<false><<<gather_blocks, 256, 0, stream>>>(cnt, ell, x, rdeg, agg);
    ovf_kernel<<<ovf_blocks, 256, 0, stream>>>(novf, ovf, x, rdeg, agg);
    dense_mfma_kernel<true><<<dense_blocks, 256, 0, stream>>>(agg, x, Wt1, b1l, out, nullptr, NN);
    gather_ell_kernel<false><<<gather_blocks, 256, 0, stream>>>(cnt, ell, out, rdeg, agg);
    ovf_kernel<<<ovf_blocks, 256, 0, stream>>>(novf, ovf, out, rdeg, agg);
    dense_mfma_kernel<false><<<dense_blocks, 256, 0, stream>>>(agg, out, Wt2, b2l, out, nullptr, NN);
  }
}

// Round 5
// 402.403 us; speedup vs baseline: 14.3937x; 1.0976x over previous
//
#include <hip/hip_runtime.h>
#include <cstdint>
#include <cstddef>

#define NN 100000
#define EE 1600000
#define DIM 128
#define CAP 48        // ELL row capacity (mean deg 16; P(deg>48) ~ 5e-11 per node)
#define OVF_CAP 2048  // overflow edge capacity (expected 0 used)

typedef __attribute__((ext_vector_type(8))) short bf16x8;
typedef __attribute__((ext_vector_type(4))) float f32x4;

__device__ __forceinline__ unsigned short f2bf(float f) {
  union { float f; uint32_t u; } v; v.f = f;
  uint32_t r = v.u + 0x7FFF + ((v.u >> 16) & 1);  // RNE to bf16
  return (unsigned short)(r >> 16);
}
__device__ __forceinline__ float bf2f(unsigned short s) {
  union { uint32_t u; float f; } v; v.u = (uint32_t)s << 16;
  return v.f;
}

// ---------------------------------------------------------------------------
// Edge-index loads: handle both int32 and int64 storage.
// ---------------------------------------------------------------------------
__global__ void detect_i64_kernel(const int* __restrict__ e32, int* __restrict__ flag) {
  __shared__ int any_nz;
  if (threadIdx.x == 0) any_nz = 0;
  __syncthreads();
  if (e32[2 * threadIdx.x + 1] != 0) any_nz = 1;
  __syncthreads();
  if (threadIdx.x == 0) *flag = (any_nz == 0) ? 1 : 0;
}

// ---------------------------------------------------------------------------
// ELL fill: one atomic pass builds neighbor lists AND degree counts.
// 4 edges per thread for memory-level parallelism (independent atomic chains).
// ---------------------------------------------------------------------------
__global__ __launch_bounds__(256) void ellfill_kernel(
    const void* __restrict__ edges, const int* __restrict__ i64f,
    int* __restrict__ cnt, int* __restrict__ ell,
    int* __restrict__ novf, int* __restrict__ ovf) {
  int e0 = (blockIdx.x * 256 + threadIdx.x) * 4;
  if (e0 >= EE) return;  // EE % 4 == 0, so e0..e0+3 all valid when e0 < EE
  int i64 = *i64f;
  int s[4], d[4];
  if (!i64) {
    const int* e32 = (const int*)edges;
    int4 sv = *(const int4*)(e32 + e0);
    int4 dv = *(const int4*)(e32 + EE + e0);
    s[0] = sv.x; s[1] = sv.y; s[2] = sv.z; s[3] = sv.w;
    d[0] = dv.x; d[1] = dv.y; d[2] = dv.z; d[3] = dv.w;
  } else {
    const long long* e64 = (const long long*)edges;
#pragma unroll
    for (int i = 0; i < 4; ++i) {
      s[i] = (int)e64[e0 + i];
      d[i] = (int)e64[(long long)EE + e0 + i];
    }
  }
  int pos[4];
#pragma unroll
  for (int i = 0; i < 4; ++i)
    pos[i] = ((unsigned)s[i] < NN && (unsigned)d[i] < NN) ? atomicAdd(&cnt[d[i]], 1) : -1;
#pragma unroll
  for (int i = 0; i < 4; ++i) {
    if (pos[i] < 0) continue;
    if (pos[i] < CAP) {
      ell[(size_t)d[i] * CAP + pos[i]] = s[i];
    } else {
      int oi = atomicAdd(novf, 1);
      if (oi < OVF_CAP) { ovf[oi * 2] = s[i]; ovf[oi * 2 + 1] = d[i]; }
    }
  }
}

// ---------------------------------------------------------------------------
// x (f32) -> bf16 hi/lo planes (exact split: hi + lo == x to ~2^-18 rel)
// ---------------------------------------------------------------------------
__global__ void cast2_kernel(const float* __restrict__ x,
                             unsigned short* __restrict__ xhi,
                             unsigned short* __restrict__ xlo) {
  int i = blockIdx.x * 256 + threadIdx.x;  // one float4 per thread
  if (i >= NN * DIM / 4) return;
  f32x4 v = ((const f32x4*)x)[i];
  ushort4 hi, lo;
  hi.x = f2bf(v[0]); lo.x = f2bf(v[0] - bf2f(hi.x));
  hi.y = f2bf(v[1]); lo.y = f2bf(v[1] - bf2f(hi.y));
  hi.z = f2bf(v[2]); lo.z = f2bf(v[2] - bf2f(hi.z));
  hi.w = f2bf(v[3]); lo.w = f2bf(v[3] - bf2f(hi.w));
  ((ushort4*)xhi)[i] = hi;
  ((ushort4*)xlo)[i] = lo;
}

// ---------------------------------------------------------------------------
// Gather-aggregate from ELL (bf16-hi input plane -> bf16-hi agg plane).
// One wave per node; halves take alternating neighbors; lane owns 4 cols.
// Overflow edges (cnt > CAP) folded in via tiny list scan (expected empty).
// ---------------------------------------------------------------------------
__global__ __launch_bounds__(256) void gather_ell_kernel(
    const int* __restrict__ cnt, const int* __restrict__ ell,
    const unsigned short* __restrict__ h, unsigned short* __restrict__ ahi,
    const int* __restrict__ novf, const int* __restrict__ ovf) {
  const int node = blockIdx.x * 4 + (threadIdx.x >> 6);
  const int lane = threadIdx.x & 63;
  const int half = lane >> 5;
  const int c = lane & 31;
  if (node >= NN) return;
  const int dcnt = cnt[node];
  const int n = dcnt < CAP ? dcnt : CAP;
  const int* row = ell + (size_t)node * CAP;
  f32x4 s = {0.f, 0.f, 0.f, 0.f};
  int p = half;
  for (; p + 2 < n; p += 4) {
    int s0 = row[p];
    int s1 = row[p + 2];
    ushort4 v0 = *(const ushort4*)(h + (size_t)s0 * DIM + c * 4);
    ushort4 v1 = *(const ushort4*)(h + (size_t)s1 * DIM + c * 4);
    s[0] += bf2f(v0.x) + bf2f(v1.x);
    s[1] += bf2f(v0.y) + bf2f(v1.y);
    s[2] += bf2f(v0.z) + bf2f(v1.z);
    s[3] += bf2f(v0.w) + bf2f(v1.w);
  }
  if (p < n) {
    ushort4 v0 = *(const ushort4*)(h + (size_t)row[p] * DIM + c * 4);
    s[0] += bf2f(v0.x);
    s[1] += bf2f(v0.y);
    s[2] += bf2f(v0.z);
    s[3] += bf2f(v0.w);
  }
#pragma unroll
  for (int i = 0; i < 4; ++i) s[i] += __shfl_xor(s[i], 32, 64);
  if (half == 0) {
    if (dcnt > CAP) {  // overflow fixup: scan tiny list (expected empty)
      int no = *novf;
      if (no > OVF_CAP) no = OVF_CAP;
      for (int i = 0; i < no; ++i) {
        if (ovf[i * 2 + 1] == node) {
          ushort4 v0 = *(const ushort4*)(h + (size_t)ovf[i * 2] * DIM + c * 4);
          s[0] += bf2f(v0.x);
          s[1] += bf2f(v0.y);
          s[2] += bf2f(v0.z);
          s[3] += bf2f(v0.w);
        }
      }
    }
    const float rd = 1.0f / fmaxf((float)dcnt, 1.0f);
    ushort4 o;
    o.x = f2bf(s[0] * rd);
    o.y = f2bf(s[1] * rd);
    o.z = f2bf(s[2] * rd);
    o.w = f2bf(s[3] * rd);
    *(ushort4*)(ahi + (size_t)node * DIM + c * 4) = o;
  }
}

// ---------------------------------------------------------------------------
// Weight prep: Wt[mat][n][k] = bf16(W[k][n])  (transposed, bf16)
// ---------------------------------------------------------------------------
__global__ void wprep_kernel(const float* __restrict__ Wl, const float* __restrict__ Wr,
                             unsigned short* __restrict__ Wt) {
  int idx = blockIdx.x * 256 + threadIdx.x;  // 32768 total
  int mat = idx >> 14;
  int r = idx & 16383;
  int k = r >> 7, n = r & 127;
  const float* W = mat ? Wr : Wl;
  Wt[((size_t)(mat * 128 + n)) * 128 + k] = f2bf(W[k * 128 + n]);
}

// ---------------------------------------------------------------------------
// Dense via MFMA: out = act(agg_hi @ Wl + bl + (h_hi + h_lo) @ Wr)
// All inputs pre-split bf16 planes -> 3 loads + 3 MFMAs per fragment, no VALU
// conversion. 64 rows x 128 cols per block (4 waves, wave owns 2 col-tiles).
// WPLANES: epilogue writes result as hi/lo planes (for next layer).
// WOUT: epilogue writes f32 result.
// ---------------------------------------------------------------------------
template <bool RELU, bool WPLANES, bool WOUT>
__global__ __launch_bounds__(256, 2) void dense_mfma_kernel(
    const unsigned short* __restrict__ ahi, const unsigned short* __restrict__ hhi,
    const unsigned short* __restrict__ hlo, const unsigned short* __restrict__ Wt,
    const float* __restrict__ bl, float* __restrict__ out,
    unsigned short* __restrict__ phi, unsigned short* __restrict__ plo, int n) {
  const int t = threadIdx.x;
  const int wave = t >> 6, lane = t & 63;
  const int l15 = lane & 15, l4 = lane >> 4;
  const int base = blockIdx.x * 64;

  bf16x8 bfr[2][4][2];
#pragma unroll
  for (int mat = 0; mat < 2; ++mat)
#pragma unroll
    for (int kt = 0; kt < 4; ++kt)
#pragma unroll
      for (int ntl = 0; ntl < 2; ++ntl) {
        int ncol = (wave * 2 + ntl) * 16 + l15;
        int k0 = kt * 32 + l4 * 8;
        bfr[mat][kt][ntl] = *(const bf16x8*)(Wt + ((size_t)(mat * 128 + ncol)) * 128 + k0);
      }

  f32x4 acc[4][2];
#pragma unroll
  for (int ntl = 0; ntl < 2; ++ntl) {
    float b = bl[(wave * 2 + ntl) * 16 + l15];
#pragma unroll
    for (int rt = 0; rt < 4; ++rt) {
      f32x4 ib = {b, b, b, b};
      acc[rt][ntl] = ib;
    }
  }

#pragma unroll
  for (int kt = 0; kt < 4; ++kt) {
    const int k0 = kt * 32 + l4 * 8;
#pragma unroll
    for (int rt = 0; rt < 4; ++rt) {
      int row = base + rt * 16 + l15;
      if (row >= n) row = n - 1;  // clamp: padded rows computed but never stored
      const size_t off = (size_t)row * DIM + k0;
      bf16x8 a8 = *(const bf16x8*)(ahi + off);
      bf16x8 hh8 = *(const bf16x8*)(hhi + off);
      bf16x8 hl8 = *(const bf16x8*)(hlo + off);
#pragma unroll
      for (int ntl = 0; ntl < 2; ++ntl) {
        acc[rt][ntl] = __builtin_amdgcn_mfma_f32_16x16x32_bf16(a8, bfr[0][kt][ntl], acc[rt][ntl], 0, 0, 0);
        acc[rt][ntl] = __builtin_amdgcn_mfma_f32_16x16x32_bf16(hh8, bfr[1][kt][ntl], acc[rt][ntl], 0, 0, 0);
        acc[rt][ntl] = __builtin_amdgcn_mfma_f32_16x16x32_bf16(hl8, bfr[1][kt][ntl], acc[rt][ntl], 0, 0, 0);
      }
    }
  }

  __syncthreads();  // all plane reads complete before in-place plane writes

#pragma unroll
  for (int rt = 0; rt < 4; ++rt)
#pragma unroll
    for (int ntl = 0; ntl < 2; ++ntl) {
      const int col = (wave * 2 + ntl) * 16 + l15;
#pragma unroll
      for (int r = 0; r < 4; ++r) {
        int row = base + rt * 16 + l4 * 4 + r;
        if (row < n) {
          float v = acc[rt][ntl][r];
          if (RELU) v = fmaxf(v, 0.f);
          const size_t off = (size_t)row * DIM + col;
          if (WOUT) out[off] = v;
          if (WPLANES) {
            unsigned short hi = f2bf(v);
            phi[off] = hi;
            plo[off] = f2bf(v - bf2f(hi));
          }
        }
      }
    }
}

// ---------------------------------------------------------------------------
extern "C" void kernel_launch(void* const* d_in, const int* in_sizes, int n_in,
                              void* d_out, int out_size, void* d_ws, size_t ws_size,
                              hipStream_t stream) {
  const float* x   = (const float*)d_in[0];
  const void* edges = d_in[1];
  const float* W1l = (const float*)d_in[2];
  const float* b1l = (const float*)d_in[3];
  const float* W1r = (const float*)d_in[4];
  const float* W2l = (const float*)d_in[5];
  const float* b2l = (const float*)d_in[6];
  const float* W2r = (const float*)d_in[7];
  float* out = (float*)d_out;

  // ---- workspace layout (total ~96.5 MB; round-4 proved >= 97.0 MB exists)
  char* p = (char*)d_ws;
  unsigned short* Wt1 = (unsigned short*)p;               p += 2 * 128 * 128 * 2;
  unsigned short* Wt2 = (unsigned short*)p;               p += 2 * 128 * 128 * 2;
  int* cnt  = (int*)p;                                    p += (size_t)NN * 4;
  int* novf = (int*)p;                                    p += 4;
  int* flag = (int*)p;                                    p += 4;
  p = (char*)(((uintptr_t)p + 15) & ~(uintptr_t)15);
  int* ovf = (int*)p;                                     p += (size_t)OVF_CAP * 2 * 4;
  p = (char*)(((uintptr_t)p + 255) & ~(uintptr_t)255);
  int* ell = (int*)p;                                     p += (size_t)NN * CAP * 4;
  p = (char*)(((uintptr_t)p + 255) & ~(uintptr_t)255);
  unsigned short* hhi = (unsigned short*)p;               p += (size_t)NN * DIM * 2;
  unsigned short* hlo = (unsigned short*)p;               p += (size_t)NN * DIM * 2;
  unsigned short* ahi = (unsigned short*)p;               p += (size_t)NN * DIM * 2;

  // zero cnt + novf + flag in one memset
  hipMemsetAsync(cnt, 0, ((size_t)NN + 2) * 4, stream);

  detect_i64_kernel<<<1, 256, 0, stream>>>((const int*)edges, flag);
  ellfill_kernel<<<(EE / 4 + 255) / 256, 256, 0, stream>>>(edges, flag, cnt, ell, novf, ovf);

  wprep_kernel<<<128, 256, 0, stream>>>(W1l, W1r, Wt1);
  wprep_kernel<<<128, 256, 0, stream>>>(W2l, W2r, Wt2);
  cast2_kernel<<<(NN * DIM / 4 + 255) / 256, 256, 0, stream>>>(x, hhi, hlo);

  const int gather_blocks = (NN + 3) / 4;
  const int dense_blocks = (NN + 63) / 64;

  // ---- layer 1: h1 = relu(mean_agg(x) @ W1l + b1l + x @ W1r) -> hi/lo planes
  gather_ell_kernel<<<gather_blocks, 256, 0, stream>>>(cnt, ell, hhi, ahi, novf, ovf);
  dense_mfma_kernel<true, true, false><<<dense_blocks, 256, 0, stream>>>(
      ahi, hhi, hlo, Wt1, b1l, out, hhi, hlo, NN);

  // ---- layer 2: out = mean_agg(h1) @ W2l + b2l + h1 @ W2r -> f32 out
  gather_ell_kernel<<<gather_blocks, 256, 0, stream>>>(cnt, ell, hhi, ahi, novf, ovf);
  dense_mfma_kernel<false, false, true><<<dense_blocks, 256, 0, stream>>>(
      ahi, hhi, hlo, Wt2, b2l, out, nullptr, nullptr, NN);
}

// Round 6
// 374.464 us; speedup vs baseline: 15.4677x; 1.0746x over previous
//
#include <hip/hip_runtime.h>
#include <cstdint>
#include <cstddef>

#define NN 100000
#define EE 1600000
#define DIM 128
#define CAP 48        // ELL row capacity (mean deg 16; P(deg>48) ~ 5e-11 per node)
#define OVF_CAP 512   // overflow edge capacity (expected 0 used)

#define NB 391        // dst buckets of 256 nodes: ceil(100000/256)
#define BCAP 4608     // per-bucket partition capacity (mean 4092, +8 sigma)
#define SLOTS 32      // LDS staging slots per bucket
#define FLUSH_AT 16   // flush threshold (entries)
#define ACHUNK 8192   // edges per phase-A block

typedef __attribute__((ext_vector_type(8))) short bf16x8;
typedef __attribute__((ext_vector_type(4))) float f32x4;

__device__ __forceinline__ unsigned short f2bf(float f) {
  union { float f; uint32_t u; } v; v.f = f;
  uint32_t r = v.u + 0x7FFF + ((v.u >> 16) & 1);  // RNE to bf16
  return (unsigned short)(r >> 16);
}
__device__ __forceinline__ float bf2f(unsigned short s) {
  union { uint32_t u; float f; } v; v.u = (uint32_t)s << 16;
  return v.f;
}

// ---------------------------------------------------------------------------
// Edge-index dtype detection (int64 vs int32 storage).
// ---------------------------------------------------------------------------
__global__ void detect_i64_kernel(const int* __restrict__ e32, int* __restrict__ flag) {
  __shared__ int any_nz;
  if (threadIdx.x == 0) any_nz = 0;
  __syncthreads();
  if (e32[2 * threadIdx.x + 1] != 0) any_nz = 1;
  __syncthreads();
  if (threadIdx.x == 0) *flag = (any_nz == 0) ? 1 : 0;
}

// ---------------------------------------------------------------------------
// Phase A: partition edges into NB dst-buckets with LDS staging.
// pack = s | ((d & 255) << 17)   (s < 2^17, NN = 100000 < 131072)
// ---------------------------------------------------------------------------
__global__ __launch_bounds__(256) void partA_kernel(
    const void* __restrict__ edges, const int* __restrict__ i64f,
    int* __restrict__ bcnt, unsigned* __restrict__ part,
    int* __restrict__ novf, int* __restrict__ ovf) {
  __shared__ unsigned stage[NB][SLOTS];
  __shared__ int scnt[NB];
  const int t = threadIdx.x;
  for (int b = t; b < NB; b += 256) scnt[b] = 0;
  __syncthreads();
  const int i64 = *i64f;
  const long long ebase = (long long)blockIdx.x * ACHUNK;
  const int nrounds = ACHUNK / 256;
  for (int r = 0; r < nrounds; ++r) {
    long long e = ebase + r * 256 + t;
    if (e < EE) {
      int s, d;
      if (i64) {
        s = (int)((const long long*)edges)[e];
        d = (int)((const long long*)edges)[(long long)EE + e];
      } else {
        s = ((const int*)edges)[e];
        d = ((const int*)edges)[EE + e];
      }
      if ((unsigned)s < NN && (unsigned)d < NN) {
        int b = d >> 8;
        unsigned pk = (unsigned)s | ((unsigned)(d & 255) << 17);
        int pos = atomicAdd(&scnt[b], 1);
        if (pos < SLOTS) {
          stage[b][pos] = pk;
        } else {  // stage overflow (astronomically rare): direct append
          int g = atomicAdd(&bcnt[b], 1);
          if (g < BCAP) part[(size_t)b * BCAP + g] = pk;
          else { int oi = atomicAdd(novf, 1); if (oi < OVF_CAP) { ovf[oi*2] = s; ovf[oi*2+1] = d; } }
        }
      }
    }
    __syncthreads();
    const bool last = (r == nrounds - 1);
    for (int b = t; b < NB; b += 256) {
      int c = scnt[b];
      if (c > SLOTS) c = SLOTS;
      if (c > 0 && (c >= FLUSH_AT || last)) {
        int g = atomicAdd(&bcnt[b], c);
        for (int i = 0; i < c; ++i) {
          int gp = g + i;
          if (gp < BCAP) part[(size_t)b * BCAP + gp] = stage[b][i];
          else {
            int s2 = (int)(stage[b][i] & 0x1FFFF);
            int d2 = (b << 8) | (int)(stage[b][i] >> 17);
            int oi = atomicAdd(novf, 1);
            if (oi < OVF_CAP) { ovf[oi*2] = s2; ovf[oi*2+1] = d2; }
          }
        }
        scnt[b] = 0;
      }
    }
    __syncthreads();
  }
}

// ---------------------------------------------------------------------------
// Phase B: per bucket, build 256 ELL rows in LDS (LDS atomics), write densely.
// ---------------------------------------------------------------------------
__global__ __launch_bounds__(256) void partB_kernel(
    const int* __restrict__ bcnt, const unsigned* __restrict__ part,
    int* __restrict__ cnt, int* __restrict__ ell,
    int* __restrict__ novf, int* __restrict__ ovf) {
  __shared__ int lcnt[256];
  __shared__ int lell[256 * CAP];  // 48 KB
  const int t = threadIdx.x;
  const int b = blockIdx.x;
  lcnt[t] = 0;
  __syncthreads();
  int n = bcnt[b];
  if (n > BCAP) n = BCAP;
  for (int i = t; i < n; i += 256) {
    unsigned pk = part[(size_t)b * BCAP + i];
    int s = (int)(pk & 0x1FFFF);
    int dl = (int)(pk >> 17);
    int pos = atomicAdd(&lcnt[dl], 1);
    if (pos < CAP) lell[dl * CAP + pos] = s;
    else { int oi = atomicAdd(novf, 1); if (oi < OVF_CAP) { ovf[oi*2] = s; ovf[oi*2+1] = (b << 8) | dl; } }
  }
  __syncthreads();
  // dense coalesced ELL write: global flat base = b * 256 * CAP
  const int4* src = (const int4*)lell;
  int4* dst = (int4*)(ell + (size_t)b * 256 * CAP);
#pragma unroll
  for (int i = 0; i < 256 * CAP / 4 / 256; ++i) dst[t + i * 256] = src[t + i * 256];
  int node = b * 256 + t;
  if (node < NN) cnt[node] = lcnt[t];
}

// ---------------------------------------------------------------------------
// x (f32) -> bf16 hi/lo planes (exact split)
// ---------------------------------------------------------------------------
__global__ void cast2_kernel(const float* __restrict__ x,
                             unsigned short* __restrict__ xhi,
                             unsigned short* __restrict__ xlo) {
  int i = blockIdx.x * 256 + threadIdx.x;  // one float4 per thread
  if (i >= NN * DIM / 4) return;
  f32x4 v = ((const f32x4*)x)[i];
  ushort4 hi, lo;
  hi.x = f2bf(v[0]); lo.x = f2bf(v[0] - bf2f(hi.x));
  hi.y = f2bf(v[1]); lo.y = f2bf(v[1] - bf2f(hi.y));
  hi.z = f2bf(v[2]); lo.z = f2bf(v[2] - bf2f(hi.z));
  hi.w = f2bf(v[3]); lo.w = f2bf(v[3] - bf2f(hi.w));
  ((ushort4*)xhi)[i] = hi;
  ((ushort4*)xlo)[i] = lo;
}

// ---------------------------------------------------------------------------
// Gather-aggregate from ELL (bf16-hi input plane -> bf16-hi agg plane).
// One wave per node; halves take alternating neighbors; lane owns 4 cols.
// ---------------------------------------------------------------------------
__global__ __launch_bounds__(256) void gather_ell_kernel(
    const int* __restrict__ cnt, const int* __restrict__ ell,
    const unsigned short* __restrict__ h, unsigned short* __restrict__ ahi,
    const int* __restrict__ novf, const int* __restrict__ ovf) {
  const int node = blockIdx.x * 4 + (threadIdx.x >> 6);
  const int lane = threadIdx.x & 63;
  const int half = lane >> 5;
  const int c = lane & 31;
  if (node >= NN) return;
  const int dcnt = cnt[node];
  const int n = dcnt < CAP ? dcnt : CAP;
  const int* row = ell + (size_t)node * CAP;
  f32x4 s = {0.f, 0.f, 0.f, 0.f};
  int p = half;
  for (; p + 2 < n; p += 4) {
    int s0 = row[p];
    int s1 = row[p + 2];
    ushort4 v0 = *(const ushort4*)(h + (size_t)s0 * DIM + c * 4);
    ushort4 v1 = *(const ushort4*)(h + (size_t)s1 * DIM + c * 4);
    s[0] += bf2f(v0.x) + bf2f(v1.x);
    s[1] += bf2f(v0.y) + bf2f(v1.y);
    s[2] += bf2f(v0.z) + bf2f(v1.z);
    s[3] += bf2f(v0.w) + bf2f(v1.w);
  }
  if (p < n) {
    ushort4 v0 = *(const ushort4*)(h + (size_t)row[p] * DIM + c * 4);
    s[0] += bf2f(v0.x);
    s[1] += bf2f(v0.y);
    s[2] += bf2f(v0.z);
    s[3] += bf2f(v0.w);
  }
#pragma unroll
  for (int i = 0; i < 4; ++i) s[i] += __shfl_xor(s[i], 32, 64);
  if (half == 0) {
    if (dcnt > CAP) {  // overflow fixup: scan tiny list (expected empty)
      int no = *novf;
      if (no > OVF_CAP) no = OVF_CAP;
      for (int i = 0; i < no; ++i) {
        if (ovf[i * 2 + 1] == node) {
          ushort4 v0 = *(const ushort4*)(h + (size_t)ovf[i * 2] * DIM + c * 4);
          s[0] += bf2f(v0.x);
          s[1] += bf2f(v0.y);
          s[2] += bf2f(v0.z);
          s[3] += bf2f(v0.w);
        }
      }
    }
    const float rd = 1.0f / fmaxf((float)dcnt, 1.0f);
    ushort4 o;
    o.x = f2bf(s[0] * rd);
    o.y = f2bf(s[1] * rd);
    o.z = f2bf(s[2] * rd);
    o.w = f2bf(s[3] * rd);
    *(ushort4*)(ahi + (size_t)node * DIM + c * 4) = o;
  }
}

// ---------------------------------------------------------------------------
// Weight prep: Wt[mat][n][k] = bf16(W[k][n])  (transposed, bf16)
// ---------------------------------------------------------------------------
__global__ void wprep_kernel(const float* __restrict__ Wl, const float* __restrict__ Wr,
                             unsigned short* __restrict__ Wt) {
  int idx = blockIdx.x * 256 + threadIdx.x;  // 32768 total
  int mat = idx >> 14;
  int r = idx & 16383;
  int k = r >> 7, n = r & 127;
  const float* W = mat ? Wr : Wl;
  Wt[((size_t)(mat * 128 + n)) * 128 + k] = f2bf(W[k * 128 + n]);
}

// ---------------------------------------------------------------------------
// Dense via MFMA: out = act(agg_hi @ Wl + bl + (h_hi + h_lo) @ Wr)
// ---------------------------------------------------------------------------
template <bool RELU, bool WPLANES, bool WOUT>
__global__ __launch_bounds__(256, 2) void dense_mfma_kernel(
    const unsigned short* __restrict__ ahi, const unsigned short* __restrict__ hhi,
    const unsigned short* __restrict__ hlo, const unsigned short* __restrict__ Wt,
    const float* __restrict__ bl, float* __restrict__ out,
    unsigned short* __restrict__ phi, unsigned short* __restrict__ plo, int n) {
  const int t = threadIdx.x;
  const int wave = t >> 6, lane = t & 63;
  const int l15 = lane & 15, l4 = lane >> 4;
  const int base = blockIdx.x * 64;

  bf16x8 bfr[2][4][2];
#pragma unroll
  for (int mat = 0; mat < 2; ++mat)
#pragma unroll
    for (int kt = 0; kt < 4; ++kt)
#pragma unroll
      for (int ntl = 0; ntl < 2; ++ntl) {
        int ncol = (wave * 2 + ntl) * 16 + l15;
        int k0 = kt * 32 + l4 * 8;
        bfr[mat][kt][ntl] = *(const bf16x8*)(Wt + ((size_t)(mat * 128 + ncol)) * 128 + k0);
      }

  f32x4 acc[4][2];
#pragma unroll
  for (int ntl = 0; ntl < 2; ++ntl) {
    float b = bl[(wave * 2 + ntl) * 16 + l15];
#pragma unroll
    for (int rt = 0; rt < 4; ++rt) {
      f32x4 ib = {b, b, b, b};
      acc[rt][ntl] = ib;
    }
  }

#pragma unroll
  for (int kt = 0; kt < 4; ++kt) {
    const int k0 = kt * 32 + l4 * 8;
#pragma unroll
    for (int rt = 0; rt < 4; ++rt) {
      int row = base + rt * 16 + l15;
      if (row >= n) row = n - 1;  // clamp: padded rows computed but never stored
      const size_t off = (size_t)row * DIM + k0;
      bf16x8 a8 = *(const bf16x8*)(ahi + off);
      bf16x8 hh8 = *(const bf16x8*)(hhi + off);
      bf16x8 hl8 = *(const bf16x8*)(hlo + off);
#pragma unroll
      for (int ntl = 0; ntl < 2; ++ntl) {
        acc[rt][ntl] = __builtin_amdgcn_mfma_f32_16x16x32_bf16(a8, bfr[0][kt][ntl], acc[rt][ntl], 0, 0, 0);
        acc[rt][ntl] = __builtin_amdgcn_mfma_f32_16x16x32_bf16(hh8, bfr[1][kt][ntl], acc[rt][ntl], 0, 0, 0);
        acc[rt][ntl] = __builtin_amdgcn_mfma_f32_16x16x32_bf16(hl8, bfr[1][kt][ntl], acc[rt][ntl], 0, 0, 0);
      }
    }
  }

  __syncthreads();  // all plane reads complete before in-place plane writes

#pragma unroll
  for (int rt = 0; rt < 4; ++rt)
#pragma unroll
    for (int ntl = 0; ntl < 2; ++ntl) {
      const int col = (wave * 2 + ntl) * 16 + l15;
#pragma unroll
      for (int r = 0; r < 4; ++r) {
        int row = base + rt * 16 + l4 * 4 + r;
        if (row < n) {
          float v = acc[rt][ntl][r];
          if (RELU) v = fmaxf(v, 0.f);
          const size_t off = (size_t)row * DIM + col;
          if (WOUT) out[off] = v;
          if (WPLANES) {
            unsigned short hi = f2bf(v);
            phi[off] = hi;
            plo[off] = f2bf(v - bf2f(hi));
          }
        }
      }
    }
}

// ---------------------------------------------------------------------------
extern "C" void kernel_launch(void* const* d_in, const int* in_sizes, int n_in,
                              void* d_out, int out_size, void* d_ws, size_t ws_size,
                              hipStream_t stream) {
  const float* x   = (const float*)d_in[0];
  const void* edges = d_in[1];
  const float* W1l = (const float*)d_in[2];
  const float* b1l = (const float*)d_in[3];
  const float* W1r = (const float*)d_in[4];
  const float* W2l = (const float*)d_in[5];
  const float* b2l = (const float*)d_in[6];
  const float* W2r = (const float*)d_in[7];
  float* out = (float*)d_out;

  // ---- workspace layout (total ~96.6 MB; partition buffer aliases ahi)
  char* p = (char*)d_ws;
  unsigned short* Wt1 = (unsigned short*)p;               p += 2 * 128 * 128 * 2;
  unsigned short* Wt2 = (unsigned short*)p;               p += 2 * 128 * 128 * 2;
  int* cnt  = (int*)p;                                    p += (size_t)NN * 4;
  int* bcnt = (int*)p;                                    p += (size_t)NB * 4;
  int* novf = (int*)p;                                    p += 4;
  int* flag = (int*)p;                                    p += 4;
  p = (char*)(((uintptr_t)p + 15) & ~(uintptr_t)15);
  int* ovf = (int*)p;                                     p += (size_t)OVF_CAP * 2 * 4;
  p = (char*)(((uintptr_t)p + 255) & ~(uintptr_t)255);
  int* ell = (int*)p;                                     p += (size_t)NB * 256 * CAP * 4;  // padded ELL
  p = (char*)(((uintptr_t)p + 255) & ~(uintptr_t)255);
  unsigned short* hhi = (unsigned short*)p;               p += (size_t)NN * DIM * 2;
  unsigned short* hlo = (unsigned short*)p;               p += (size_t)NN * DIM * 2;
  unsigned short* ahi = (unsigned short*)p;               p += (size_t)NN * DIM * 2;
  unsigned* part = (unsigned*)ahi;  // alias: part dead before first write to ahi

  // zero bcnt + novf + flag in one memset (cnt fully rewritten by partB)
  hipMemsetAsync(bcnt, 0, ((size_t)NB + 2) * 4, stream);

  detect_i64_kernel<<<1, 256, 0, stream>>>((const int*)edges, flag);
  partA_kernel<<<(EE + ACHUNK - 1) / ACHUNK, 256, 0, stream>>>(edges, flag, bcnt, part, novf, ovf);
  partB_kernel<<<NB, 256, 0, stream>>>(bcnt, part, cnt, ell, novf, ovf);

  wprep_kernel<<<128, 256, 0, stream>>>(W1l, W1r, Wt1);
  wprep_kernel<<<128, 256, 0, stream>>>(W2l, W2r, Wt2);
  cast2_kernel<<<(NN * DIM / 4 + 255) / 256, 256, 0, stream>>>(x, hhi, hlo);

  const int gather_blocks = (NN + 3) / 4;
  const int dense_blocks = (NN + 63) / 64;

  // ---- layer 1: h1 = relu(mean_agg(x) @ W1l + b1l + x @ W1r) -> hi/lo planes
  gather_ell_kernel<<<gather_blocks, 256, 0, stream>>>(cnt, ell, hhi, ahi, novf, ovf);
  dense_mfma_kernel<true, true, false><<<dense_blocks, 256, 0, stream>>>(
      ahi, hhi, hlo, Wt1, b1l, out, hhi, hlo, NN);

  // ---- layer 2: out = mean_agg(h1) @ W2l + b2l + h1 @ W2r -> f32 out
  gather_ell_kernel<<<gather_blocks, 256, 0, stream>>>(cnt, ell, hhi, ahi, novf, ovf);
  dense_mfma_kernel<false, false, true><<<dense_blocks, 256, 0, stream>>>(
      ahi, hhi, hlo, Wt2, b2l, out, nullptr, nullptr, NN);
}